// Round 1
// baseline (710.135 us; speedup 1.0000x reference)
//
#include <hip/hip_runtime.h>
#include <hip/hip_bf16.h>
#include <stdint.h>

#define DDIM 512
#define NHEAD 8
#define HDIM 64
#define BATCH 4
#define LTOK 24576
#define MROWS 98304          // BATCH * LTOK
#define NCHUNK 24
#define CHROWS 1024          // LTOK / NCHUNK

typedef __attribute__((ext_vector_type(8))) short short8;
typedef __attribute__((ext_vector_type(4))) float f32x4;

__device__ __forceinline__ float bf2f(unsigned short u) {
  union { unsigned int i; float f; } c; c.i = ((unsigned int)u) << 16; return c.f;
}
__device__ __forceinline__ unsigned short f2bf(float f) {
  union { float f; unsigned int i; } c; c.f = f;
  unsigned int r = c.i + 0x7FFFu + ((c.i >> 16) & 1u);
  return (unsigned short)(r >> 16);
}
__device__ __forceinline__ void gload16(const void* g, void* l) {
  __builtin_amdgcn_global_load_lds((const __attribute__((address_space(1))) void*)g,
                                   (__attribute__((address_space(3))) void*)l, 16, 0, 0);
}

// ---------------- weight fp32 -> bf16 ----------------
__global__ __launch_bounds__(256) void wconv(const float* __restrict__ s,
                                             unsigned short* __restrict__ d) {
  int t = blockIdx.x * 256 + threadIdx.x;
  d[t] = f2bf(s[t]);
}

// ---------------- LayerNorm fp32 -> bf16 ----------------
__global__ __launch_bounds__(256) void ln_kernel(const float* __restrict__ x,
                                                 const float* __restrict__ g,
                                                 const float* __restrict__ b,
                                                 unsigned short* __restrict__ h) {
  int wv = threadIdx.x >> 6, lane = threadIdx.x & 63;
  long row = (long)blockIdx.x * 4 + wv;
  const float* xr = x + row * DDIM + lane * 8;
  float4 v0 = *(const float4*)xr;
  float4 v1 = *(const float4*)(xr + 4);
  float s  = v0.x + v0.y + v0.z + v0.w + v1.x + v1.y + v1.z + v1.w;
  float s2 = v0.x*v0.x + v0.y*v0.y + v0.z*v0.z + v0.w*v0.w
           + v1.x*v1.x + v1.y*v1.y + v1.z*v1.z + v1.w*v1.w;
  #pragma unroll
  for (int o = 32; o; o >>= 1) { s += __shfl_xor(s, o); s2 += __shfl_xor(s2, o); }
  float mu = s * (1.0f / DDIM);
  float var = s2 * (1.0f / DDIM) - mu * mu;
  float rs = rsqrtf(var + 1e-5f);
  float4 g0 = *(const float4*)(g + lane * 8);
  float4 g1 = *(const float4*)(g + lane * 8 + 4);
  float4 b0 = *(const float4*)(b + lane * 8);
  float4 b1 = *(const float4*)(b + lane * 8 + 4);
  short8 o;
  o[0] = (short)f2bf((v0.x - mu) * rs * g0.x + b0.x);
  o[1] = (short)f2bf((v0.y - mu) * rs * g0.y + b0.y);
  o[2] = (short)f2bf((v0.z - mu) * rs * g0.z + b0.z);
  o[3] = (short)f2bf((v0.w - mu) * rs * g0.w + b0.w);
  o[4] = (short)f2bf((v1.x - mu) * rs * g1.x + b1.x);
  o[5] = (short)f2bf((v1.y - mu) * rs * g1.y + b1.y);
  o[6] = (short)f2bf((v1.z - mu) * rs * g1.z + b1.z);
  o[7] = (short)f2bf((v1.w - mu) * rs * g1.w + b1.w);
  *(short8*)(h + row * DDIM + lane * 8) = o;
}

// ---------------- GEMM: C = A @ W^T + bias (+epilogue) ----------------
// A: [M,K] bf16 row-major. W: [N,K] bf16 row-major. EPI: 0 plain bf16 out,
// 1 elu+1 bf16 out, 2 fp32 out + residual.
template <int EPI>
__global__ __launch_bounds__(256) void gemm_bt(const unsigned short* __restrict__ A,
                                               const unsigned short* __restrict__ W,
                                               const float* __restrict__ bias,
                                               const float* __restrict__ res,
                                               void* __restrict__ outp,
                                               int M, int N, int K) {
  __shared__ unsigned short As[128 * 64];
  __shared__ unsigned short Bs[128 * 64];
  int t = threadIdx.x;
  int wv = t >> 6, lane = t & 63;
  int wm = wv >> 1, wn = wv & 1;
  long mBase = (long)blockIdx.x * 128;
  int nBase = blockIdx.y * 128;
  f32x4 acc[4][4];
  #pragma unroll
  for (int m = 0; m < 4; m++)
    #pragma unroll
    for (int n = 0; n < 4; n++) acc[m][n] = (f32x4){0.f, 0.f, 0.f, 0.f};

  const unsigned short* Ab = A + mBase * K;
  const unsigned short* Wb = W + (long)nBase * K;

  for (int k0 = 0; k0 < K; k0 += 64) {
    #pragma unroll
    for (int i = 0; i < 4; i++) {
      int c = i * 256 + t;
      int r = c >> 3, kc = (c & 7) * 8;
      gload16(Ab + (long)r * K + k0 + kc, (unsigned short*)As + c * 8);
      gload16(Wb + (long)r * K + k0 + kc, (unsigned short*)Bs + c * 8);
    }
    __syncthreads();
    #pragma unroll
    for (int kk = 0; kk < 2; kk++) {
      int kl = kk * 32 + (lane >> 4) * 8;
      short8 a[4], b[4];
      #pragma unroll
      for (int m = 0; m < 4; m++)
        a[m] = *(const short8*)&As[(wm * 64 + m * 16 + (lane & 15)) * 64 + kl];
      #pragma unroll
      for (int n = 0; n < 4; n++)
        b[n] = *(const short8*)&Bs[(wn * 64 + n * 16 + (lane & 15)) * 64 + kl];
      #pragma unroll
      for (int m = 0; m < 4; m++)
        #pragma unroll
        for (int n = 0; n < 4; n++)
          acc[m][n] = __builtin_amdgcn_mfma_f32_16x16x32_bf16(a[m], b[n], acc[m][n], 0, 0, 0);
    }
    __syncthreads();
  }

  #pragma unroll
  for (int n = 0; n < 4; n++) {
    int col = nBase + wn * 64 + n * 16 + (lane & 15);
    float bv = bias[col];
    #pragma unroll
    for (int m = 0; m < 4; m++) {
      long row0 = mBase + wm * 64 + m * 16 + (lane >> 4) * 4;
      #pragma unroll
      for (int j = 0; j < 4; j++) {
        long row = row0 + j;
        float v = acc[m][n][j] + bv;
        if (EPI == 1) v = (v > 0.f) ? (v + 1.f) : __expf(v);
        if (EPI == 2) {
          ((float*)outp)[row * N + col] = v + res[row * N + col];
        } else {
          ((unsigned short*)outp)[row * N + col] = f2bf(v);
        }
      }
    }
  }
}

// ---------------- KV outer-product partial reduction ----------------
// K,V: [MROWS, 512] bf16; per (bh, chunk) -> partial kv[64][64], ksum[64]
__global__ __launch_bounds__(256) void kv_reduce(const unsigned short* __restrict__ Kb,
                                                 const unsigned short* __restrict__ Vb,
                                                 float* __restrict__ part_kv,
                                                 float* __restrict__ part_ks) {
  __shared__ unsigned short smem[2][64 * 64];  // Ks, Vs (8KB each)
  __shared__ float red2[256];
  unsigned short* Ks = smem[0];
  unsigned short* Vs = smem[1];
  int t = threadIdx.x, wv = t >> 6, lane = t & 63;
  int bh = blockIdx.x, ck = blockIdx.y;
  int bb = bh >> 3, hh = bh & 7;
  long rowBase = (long)bb * LTOK + (long)ck * CHROWS;
  int colBase = hh * 64;
  int r8 = lane >> 3, c8 = lane & 7;
  float acc[8][8];
  float ksacc[8];
  #pragma unroll
  for (int i = 0; i < 8; i++) {
    ksacc[i] = 0.f;
    #pragma unroll
    for (int j = 0; j < 8; j++) acc[i][j] = 0.f;
  }

  for (int st = 0; st < 16; st++) {
    #pragma unroll
    for (int i = 0; i < 2; i++) {
      int c = i * 256 + t;
      int sr = c >> 3, sc = (c & 7) * 8;
      long gr = rowBase + st * 64 + sr;
      *(short8*)&Ks[sr * 64 + sc] = *(const short8*)&Kb[gr * DDIM + colBase + sc];
      *(short8*)&Vs[sr * 64 + sc] = *(const short8*)&Vb[gr * DDIM + colBase + sc];
    }
    __syncthreads();
    for (int l = wv * 16; l < wv * 16 + 16; l++) {
      short8 k8 = *(const short8*)&Ks[l * 64 + r8 * 8];
      short8 v8 = *(const short8*)&Vs[l * 64 + c8 * 8];
      float kf[8], vf[8];
      #pragma unroll
      for (int i = 0; i < 8; i++) { kf[i] = bf2f((unsigned short)k8[i]); vf[i] = bf2f((unsigned short)v8[i]); }
      #pragma unroll
      for (int i = 0; i < 8; i++) {
        ksacc[i] += kf[i];
        #pragma unroll
        for (int j = 0; j < 8; j++) acc[i][j] += kf[i] * vf[j];
      }
    }
    __syncthreads();
  }

  // block-level deterministic reduce of kv into LDS (16KB overlay on smem)
  float* red = (float*)smem;
  for (int w = 0; w < 4; w++) {
    if (wv == w) {
      #pragma unroll
      for (int i = 0; i < 8; i++)
        #pragma unroll
        for (int j = 0; j < 8; j++) {
          int idx = (r8 * 8 + i) * 64 + c8 * 8 + j;
          red[idx] = (w == 0) ? acc[i][j] : red[idx] + acc[i][j];
        }
    }
    __syncthreads();
  }
  float* outp = part_kv + ((long)ck * 32 + bh) * 4096;
  for (int idx = t; idx < 4096; idx += 256) outp[idx] = red[idx];

  // ksum: lanes with c8==0 hold per-wave partials for d = r8*8+i
  if (c8 == 0) {
    #pragma unroll
    for (int i = 0; i < 8; i++) red2[wv * 64 + r8 * 8 + i] = ksacc[i];
  }
  __syncthreads();
  if (t < 64)
    part_ks[((long)ck * 32 + bh) * 64 + t] = red2[t] + red2[64 + t] + red2[128 + t] + red2[192 + t];
}

// ---------------- finalize partials: kvT bf16 [bh][e][d], ksum fp32 ----------------
__global__ __launch_bounds__(256) void kv_final(const float* __restrict__ part_kv,
                                                const float* __restrict__ part_ks,
                                                unsigned short* __restrict__ kvT,
                                                float* __restrict__ ksum) {
  int t = blockIdx.x * 256 + threadIdx.x;
  if (t < 32 * 4096) {
    int bh = t >> 12, idx = t & 4095;
    int d = idx >> 6, e = idx & 63;
    float s = 0.f;
    #pragma unroll
    for (int c = 0; c < NCHUNK; c++) s += part_kv[((long)c * 32 + bh) * 4096 + idx];
    kvT[bh * 4096 + e * 64 + d] = f2bf(s);
  } else if (t < 32 * 4096 + 32 * 64) {
    int i = t - 32 * 4096;
    int bh = i >> 6, d = i & 63;
    float s = 0.f;
    #pragma unroll
    for (int c = 0; c < NCHUNK; c++) s += part_ks[((long)c * 32 + bh) * 64 + d];
    ksum[i] = s;
  }
}

// ---------------- attn out: out = (q @ kv) / (q . ksum + eps) ----------------
__global__ __launch_bounds__(256) void attn_out(const unsigned short* __restrict__ Q,
                                                const unsigned short* __restrict__ kvT,
                                                const float* __restrict__ ksum,
                                                unsigned short* __restrict__ outb) {
  int t = threadIdx.x, wv = t >> 6, lane = t & 63;
  int bh = blockIdx.x;
  int bb = bh >> 3, hh = bh & 7;
  long row0 = (long)bb * LTOK + (long)blockIdx.y * 64 + wv * 16;
  int colB = hh * 64;
  int kg = lane >> 4, lr = lane & 15;

  const unsigned short* kvb = kvT + bh * 4096;
  short8 bfrag[2][4];
  #pragma unroll
  for (int kk = 0; kk < 2; kk++)
    #pragma unroll
    for (int n = 0; n < 4; n++)
      bfrag[kk][n] = *(const short8*)&kvb[(n * 16 + lr) * 64 + kk * 32 + kg * 8];
  float ks0[8], ks1[8];
  #pragma unroll
  for (int j = 0; j < 8; j++) {
    ks0[j] = ksum[bh * 64 + kg * 8 + j];
    ks1[j] = ksum[bh * 64 + 32 + kg * 8 + j];
  }

  const unsigned short* qr = Q + (row0 + lr) * DDIM + colB;
  short8 a0 = *(const short8*)&qr[kg * 8];
  short8 a1 = *(const short8*)&qr[32 + kg * 8];

  f32x4 acc[4];
  #pragma unroll
  for (int n = 0; n < 4; n++) acc[n] = (f32x4){0.f, 0.f, 0.f, 0.f};
  #pragma unroll
  for (int n = 0; n < 4; n++) {
    acc[n] = __builtin_amdgcn_mfma_f32_16x16x32_bf16(a0, bfrag[0][n], acc[n], 0, 0, 0);
    acc[n] = __builtin_amdgcn_mfma_f32_16x16x32_bf16(a1, bfrag[1][n], acc[n], 0, 0, 0);
  }

  float na = 0.f;
  #pragma unroll
  for (int j = 0; j < 8; j++)
    na += bf2f((unsigned short)a0[j]) * ks0[j] + bf2f((unsigned short)a1[j]) * ks1[j];
  na += __shfl_xor(na, 16);
  na += __shfl_xor(na, 32);
  // lane r (r = lane&15) now holds normalizer for row r of this 16-row group

  #pragma unroll
  for (int n = 0; n < 4; n++) {
    int col = colB + n * 16 + lr;
    #pragma unroll
    for (int j = 0; j < 4; j++) {
      int r = kg * 4 + j;
      float norm = __shfl(na, r);
      float v = acc[n][j] / (norm + 1e-6f);
      outb[(row0 + r) * DDIM + col] = f2bf(v);
    }
  }
}

// ---------------- launcher ----------------
extern "C" void kernel_launch(void* const* d_in, const int* in_sizes, int n_in,
                              void* d_out, int out_size, void* d_ws, size_t ws_size,
                              hipStream_t stream) {
  const float* x    = (const float*)d_in[0];
  const float* Wq   = (const float*)d_in[1];
  const float* bq   = (const float*)d_in[2];
  const float* Wk   = (const float*)d_in[3];
  const float* bk   = (const float*)d_in[4];
  const float* Wv   = (const float*)d_in[5];
  const float* bv   = (const float*)d_in[6];
  const float* Wo   = (const float*)d_in[7];
  const float* bo   = (const float*)d_in[8];
  const float* ln_g = (const float*)d_in[9];
  const float* ln_b = (const float*)d_in[10];

  char* ws = (char*)d_ws;
  size_t SZ = (size_t)MROWS * DDIM * 2;            // 100663296 bytes per bf16 buffer
  unsigned short* hbuf = (unsigned short*)ws;       // h
  unsigned short* buf1 = (unsigned short*)(ws + SZ);       // k, then q
  unsigned short* buf2 = (unsigned short*)(ws + 2 * SZ);   // v, then attn
  unsigned short* wbf  = (unsigned short*)(ws + 3 * SZ);   // Wq,Wk,Wv,Wo bf16
  char* p = ws + 3 * SZ + 4 * 262144 * 2;
  float* part_kv = (float*)p;                       p += (size_t)NCHUNK * 32 * 4096 * 4;
  float* part_ks = (float*)p;                       p += (size_t)NCHUNK * 32 * 64 * 4;
  float* ksum    = (float*)p;                       p += 32 * 64 * 4;
  unsigned short* kvT = (unsigned short*)p;

  // weights -> bf16
  wconv<<<1024, 256, 0, stream>>>(Wq, wbf + 0 * 262144);
  wconv<<<1024, 256, 0, stream>>>(Wk, wbf + 1 * 262144);
  wconv<<<1024, 256, 0, stream>>>(Wv, wbf + 2 * 262144);
  wconv<<<1024, 256, 0, stream>>>(Wo, wbf + 3 * 262144);

  // LayerNorm
  ln_kernel<<<MROWS / 4, 256, 0, stream>>>(x, ln_g, ln_b, hbuf);

  dim3 ggrid(MROWS / 128, DDIM / 128);
  // K projection (elu+1)
  gemm_bt<1><<<ggrid, 256, 0, stream>>>(hbuf, wbf + 1 * 262144, bk, nullptr, buf1, MROWS, DDIM, DDIM);
  // V projection
  gemm_bt<0><<<ggrid, 256, 0, stream>>>(hbuf, wbf + 2 * 262144, bv, nullptr, buf2, MROWS, DDIM, DDIM);

  // KV reduction
  kv_reduce<<<dim3(32, NCHUNK), 256, 0, stream>>>(buf1, buf2, part_kv, part_ks);
  kv_final<<<(32 * 4096 + 32 * 64 + 255) / 256, 256, 0, stream>>>(part_kv, part_ks, kvT, ksum);

  // Q projection (elu+1) — overwrite k buffer
  gemm_bt<1><<<ggrid, 256, 0, stream>>>(hbuf, wbf + 0 * 262144, bq, nullptr, buf1, MROWS, DDIM, DDIM);

  // attention output — overwrite v buffer
  attn_out<<<dim3(32, LTOK / 64), 256, 0, stream>>>(buf1, kvT, ksum, buf2);

  // output projection + bias + residual -> fp32 d_out
  gemm_bt<2><<<ggrid, 256, 0, stream>>>(buf2, wbf + 3 * 262144, bo, x, d_out, MROWS, DDIM, DDIM);
}